// Round 13
// baseline (105.951 us; speedup 1.0000x reference)
//
#include <hip/hip_runtime.h>

#define DEV __device__ __forceinline__

typedef unsigned u32;
typedef u32 u32x2 __attribute__((ext_vector_type(2)));
typedef _Float16 f16;
typedef f16   f16x8 __attribute__((ext_vector_type(8)));
typedef float f32x4 __attribute__((ext_vector_type(4)));

// ---------- DPP helpers ----------
template<int CTRL>
DEV int dpp_full(int src) {
    return __builtin_amdgcn_update_dpp(src, src, CTRL, 0xF, 0xF, false);
}
template<int CTRL, int RM, int BM>
DEV int dpp_masked(int old, int src) {
    return __builtin_amdgcn_update_dpp(old, src, CTRL, RM, BM, false);
}

// ---------- cross-lane xor-shuffle (r7-proven mix) ----------
template<int B>
DEV float lshfl(float x, bool px) {
    int xi = __float_as_int(x);
    if constexpr (B == 0) {
        return __int_as_float(dpp_full<0xB1>(xi));          // xor1
    } else if constexpr (B == 1) {
        return __int_as_float(dpp_full<0x4E>(xi));          // xor2
    } else if constexpr (B == 2) {
        return __int_as_float(__builtin_amdgcn_ds_swizzle(xi, 0x101F)); // xor4
    } else if constexpr (B == 3) {
        return __int_as_float(dpp_full<0x128>(xi));         // xor8
    } else if constexpr (B == 4) {
        return __int_as_float(__builtin_amdgcn_ds_swizzle(xi, 0x401F)); // xor16
    } else {
        u32x2 r = __builtin_amdgcn_permlane32_swap((u32)xi, (u32)xi, false, false);
        return __int_as_float((int)(px ? r.x : r.y));
    }
}

DEV bool probe32(int lane) {
    u32 p = (u32)((lane >> 5) & 1);
    u32x2 r = __builtin_amdgcn_permlane32_swap(p, p, false, false);
    return r.x == (p ^ 1u);
}

// ---------- complex pair primitives (fp32) ----------
DEV void rx_pair(float& r0, float& i0, float& r1, float& i1, float c, float s) {
    float nr0 = fmaf(c, r0,  s * i1);
    float ni0 = fmaf(c, i0, -s * r1);
    float nr1 = fmaf(c, r1,  s * i0);
    float ni1 = fmaf(c, i1, -s * r0);
    r0 = nr0; i0 = ni0; r1 = nr1; i1 = ni1;
}
DEV void ry_pair(float& r0, float& i0, float& r1, float& i1, float c, float s) {
    float nr0 = fmaf(c, r0, -s * r1);
    float ni0 = fmaf(c, i0, -s * i1);
    float nr1 = fmaf(c, r1,  s * r0);
    float ni1 = fmaf(c, i1,  s * i0);
    r0 = nr0; i0 = ni0; r1 = nr1; i1 = ni1;
}
DEV void rz_amp(float& r, float& i, float c, float ss) {
    float nr = fmaf(c, r, -ss * i);
    float ni = fmaf(c, i,  ss * r);
    r = nr; i = ni;
}

// ---------- gates on flat-index bit B (B = 7 - qubit), r7-verified ----------
template<int B>
DEV void apply_rx(float (&re)[4], float (&im)[4], int lane, bool px, float c, float s) {
    if constexpr (B == 7) {
        rx_pair(re[0], im[0], re[2], im[2], c, s);
        rx_pair(re[1], im[1], re[3], im[3], c, s);
    } else if constexpr (B == 6) {
        rx_pair(re[0], im[0], re[1], im[1], c, s);
        rx_pair(re[2], im[2], re[3], im[3], c, s);
    } else {
#pragma unroll
        for (int k = 0; k < 4; ++k) {
            float pr = lshfl<B>(re[k], px);
            float pi = lshfl<B>(im[k], px);
            re[k] = fmaf(c, re[k],  s * pi);
            im[k] = fmaf(c, im[k], -s * pr);
        }
    }
}
template<int B>
DEV void apply_ry(float (&re)[4], float (&im)[4], int lane, bool px, float c, float s) {
    if constexpr (B == 7) {
        ry_pair(re[0], im[0], re[2], im[2], c, s);
        ry_pair(re[1], im[1], re[3], im[3], c, s);
    } else if constexpr (B == 6) {
        ry_pair(re[0], im[0], re[1], im[1], c, s);
        ry_pair(re[2], im[2], re[3], im[3], c, s);
    } else {
        float ssel = ((lane >> B) & 1) ? s : -s;
#pragma unroll
        for (int k = 0; k < 4; ++k) {
            float pr = lshfl<B>(re[k], px);
            float pi = lshfl<B>(im[k], px);
            re[k] = fmaf(c, re[k], ssel * pr);
            im[k] = fmaf(c, im[k], ssel * pi);
        }
    }
}
template<int B>
DEV void apply_rz(float (&re)[4], float (&im)[4], int lane, float c, float s) {
    if constexpr (B == 7) {
        rz_amp(re[0], im[0], c, -s); rz_amp(re[1], im[1], c, -s);
        rz_amp(re[2], im[2], c,  s); rz_amp(re[3], im[3], c,  s);
    } else if constexpr (B == 6) {
        rz_amp(re[0], im[0], c, -s); rz_amp(re[1], im[1], c,  s);
        rz_amp(re[2], im[2], c, -s); rz_amp(re[3], im[3], c,  s);
    } else {
        float ss = ((lane >> B) & 1) ? s : -s;
#pragma unroll
        for (int k = 0; k < 4; ++k) rz_amp(re[k], im[k], c, ss);
    }
}
template<int BC, int BT>
DEV void apply_cnot(float (&re)[4], float (&im)[4], int lane, bool px) {
    if constexpr (BC == 7 && BT == 6) {
        float tr = re[2], ti = im[2];
        re[2] = re[3]; im[2] = im[3];
        re[3] = tr;    im[3] = ti;
    } else if constexpr (BC == 6) {
        re[1] = lshfl<5>(re[1], px); im[1] = lshfl<5>(im[1], px);
        re[3] = lshfl<5>(re[3], px); im[3] = lshfl<5>(im[3], px);
    } else if constexpr (BC == 5 && BT == 4) {
        bool ctrl = (lane >> 5) & 1;
#pragma unroll
        for (int k = 0; k < 4; ++k) {
            float pr = lshfl<4>(re[k], px);
            float pi = lshfl<4>(im[k], px);
            re[k] = ctrl ? pr : re[k];
            im[k] = ctrl ? pi : im[k];
        }
    } else if constexpr (BC == 4 && BT == 3) {
#pragma unroll
        for (int k = 0; k < 4; ++k) {
            int r = __float_as_int(re[k]), i = __float_as_int(im[k]);
            re[k] = __int_as_float(dpp_masked<0x128, 0xA, 0xF>(r, r));
            im[k] = __int_as_float(dpp_masked<0x128, 0xA, 0xF>(i, i));
        }
    } else if constexpr (BC == 3 && BT == 2) {
#pragma unroll
        for (int k = 0; k < 4; ++k) {
            int r = __float_as_int(re[k]), i = __float_as_int(im[k]);
            int tr = dpp_full<0x1B>(r), ti = dpp_full<0x1B>(i);
            re[k] = __int_as_float(dpp_masked<0x141, 0xF, 0xC>(r, tr));
            im[k] = __int_as_float(dpp_masked<0x141, 0xF, 0xC>(i, ti));
        }
    } else if constexpr (BC == 2 && BT == 1) {
#pragma unroll
        for (int k = 0; k < 4; ++k) {
            int r = __float_as_int(re[k]), i = __float_as_int(im[k]);
            re[k] = __int_as_float(dpp_masked<0x4E, 0xF, 0xA>(r, r));
            im[k] = __int_as_float(dpp_masked<0x4E, 0xF, 0xA>(i, i));
        }
    } else {
#pragma unroll
        for (int k = 0; k < 4; ++k) {
            re[k] = __int_as_float(dpp_full<0xB4>(__float_as_int(re[k])));
            im[k] = __int_as_float(dpp_full<0xB4>(__float_as_int(im[k])));
        }
    }
}

// ---------- fused kernel: U-gen (blocks 0..31) + encode + GEMM + readout ----------
// Packed B layout (r10-verified): half_index = (kb*256 + idx)*32 + (j&31), kb=j>>5.

__global__ __launch_bounds__(512, 2) void qa_fused(
    const float* __restrict__ x, const float* __restrict__ params,
    f16* __restrict__ Bre, f16* __restrict__ Bim, u32* __restrict__ flag,
    float* __restrict__ out, int batch)
{
    __shared__ __align__(16) f16 Ar[32 * 256];
    __shared__ __align__(16) f16 Ai[32 * 256];
    __shared__ float zb[4][32][8];

    int tid  = threadIdx.x;
    int w    = tid >> 6, lane = tid & 63;
    int gid  = blockIdx.x;
    bool px  = probe32(lane);

    // ================= producer phase: blocks 0..31, wave j = gid*8+w =================
    if (gid < 32) {
        int j = gid * 8 + w;

        float g[96];
#pragma unroll
        for (int t = 0; t < 48; ++t) {
            float th = params[t] * 0.5f;
            g[2 * t]     = __cosf(th);
            g[2 * t + 1] = __sinf(th);
        }

        float re[4], im[4];
#pragma unroll
        for (int k = 0; k < 4; ++k) {
            re[k] = ((j >> 6) == k && (j & 63) == lane) ? 1.f : 0.f;
            im[k] = 0.f;
        }

#define VQ(l, i) { const int jj = (l) * 24 + (i) * 3;                      \
                   apply_ry<7 - (i)>(re, im, lane, px, g[2*jj],   g[2*jj+1]); \
                   apply_rz<7 - (i)>(re, im, lane,     g[2*jj+2], g[2*jj+3]); }
#define CN(i)    apply_cnot<7 - (i), 6 - (i)>(re, im, lane, px);
#define RXQ(l,i) { const int jj = (l) * 24 + (i) * 3 + 2;                  \
                   apply_rx<7 - (i)>(re, im, lane, px, g[2*jj], g[2*jj+1]); }
#define LAYER(l) \
    VQ(l,0) CN(0) VQ(l,1) CN(1) VQ(l,2) CN(2) VQ(l,3) CN(3) \
    VQ(l,4) CN(4) VQ(l,5) CN(5) VQ(l,6) CN(6) VQ(l,7)       \
    RXQ(l,0) RXQ(l,1) RXQ(l,2) RXQ(l,3) RXQ(l,4) RXQ(l,5) RXQ(l,6) RXQ(l,7)

        LAYER(0)
        LAYER(1)
#undef LAYER
#undef RXQ
#undef CN
#undef VQ

        int kb = j >> 5, jj = j & 31;
#pragma unroll
        for (int k = 0; k < 4; ++k) {
            int idx = k * 64 + lane;
            int o = (kb * 256 + idx) * 32 + jj;
            Bre[o] = (f16)re[k];
            Bim[o] = (f16)im[k];
        }
        __threadfence();     // release B stores device-wide
        __syncthreads();     // all 8 waves of this block done
        if (tid == 0) atomicAdd(flag, 1u);
    }

    // ================= encode phase: all blocks, rows b0..b0+31 =================
    int b0 = gid * 32;
    bool active = (b0 < batch);

    if (active) {
        int pcl = __popc((u32)lane);
        const int kpc[4] = { 0, 1, 1, 2 };
#pragma unroll
        for (int e = 0; e < 4; ++e) {
            int rl = w * 4 + e;
            const float* xb = x + (b0 + rl) * 8;
            float4 xlo = *(const float4*)xb;
            float4 xhi = *(const float4*)(xb + 4);
            float c_[8], s_[8];
            __sincosf(xlo.x * 0.5f, &s_[0], &c_[0]);
            __sincosf(xlo.y * 0.5f, &s_[1], &c_[1]);
            __sincosf(xlo.z * 0.5f, &s_[2], &c_[2]);
            __sincosf(xlo.w * 0.5f, &s_[3], &c_[3]);
            __sincosf(xhi.x * 0.5f, &s_[4], &c_[4]);
            __sincosf(xhi.y * 0.5f, &s_[5], &c_[5]);
            __sincosf(xhi.z * 0.5f, &s_[6], &c_[6]);
            __sincosf(xhi.w * 0.5f, &s_[7], &c_[7]);

            float m6;
            m6  = ((lane >> 5) & 1) ? s_[2] : c_[2];
            m6 *= ((lane >> 4) & 1) ? s_[3] : c_[3];
            m6 *= ((lane >> 3) & 1) ? s_[4] : c_[4];
            m6 *= ((lane >> 2) & 1) ? s_[5] : c_[5];
            m6 *= ((lane >> 1) & 1) ? s_[6] : c_[6];
            m6 *= ( lane       & 1) ? s_[7] : c_[7];
            float kf[4] = { c_[0] * c_[1], c_[0] * s_[1], s_[0] * c_[1], s_[0] * s_[1] };
            int sw = (rl & 7) << 3;
#pragma unroll
            for (int k = 0; k < 4; ++k) {
                float mk = m6 * kf[k];
                int p = pcl + kpc[k];
                float sgn = (p & 2) ? -mk : mk;
                float vre = (p & 1) ? 0.f : sgn;
                float vim = (p & 1) ? -sgn : 0.f;
                int j  = k * 64 + lane;
                int hi = rl * 256 + (j ^ sw);
                Ar[hi] = (f16)vre;
                Ai[hi] = (f16)vim;
            }
        }
    }
    __syncthreads();

    // ================= wait for all 32 producer blocks =================
    if (tid == 0) {
        while (__hip_atomic_load(flag, __ATOMIC_ACQUIRE, __HIP_MEMORY_SCOPE_AGENT) < 32u)
            __builtin_amdgcn_s_sleep(2);
    }
    __syncthreads();
    __threadfence();         // acquire: invalidate caches before reading B

    if (!active) return;

    // ================= K loop: 8 steps of 32, 16 MFMAs each =================
    f32x4 accre[4], accim[4];
#pragma unroll
    for (int t = 0; t < 4; ++t) { accre[t] = (f32x4)0.f; accim[t] = (f32x4)0.f; }

    int rg   = w >> 2, cg = w & 3;
    int colbase = cg * 64 + (lane & 15);
    int arow    = rg * 16 + (lane & 15);
    int kg      = lane >> 4;
    const f16x8* B8re = reinterpret_cast<const f16x8*>(Bre);
    const f16x8* B8im = reinterpret_cast<const f16x8*>(Bim);

#pragma unroll
    for (int kb = 0; kb < 8; ++kb) {
        int afi = arow * 32 + ((kb * 4 + kg) ^ (arow & 7));
        f16x8 are = *reinterpret_cast<const f16x8*>(&Ar[afi * 8]);
        f16x8 aim = *reinterpret_cast<const f16x8*>(&Ai[afi * 8]);
        f16x8 ain;
#pragma unroll
        for (int i = 0; i < 8; ++i) ain[i] = -aim[i];
#pragma unroll
        for (int t = 0; t < 4; ++t) {
            int idx = colbase + t * 16;
            int bo  = (kb * 256 + idx) * 4 + kg;
            f16x8 bre = B8re[bo];
            f16x8 bim = B8im[bo];
            accre[t] = __builtin_amdgcn_mfma_f32_16x16x32_f16(are, bre, accre[t], 0, 0, 0);
            accre[t] = __builtin_amdgcn_mfma_f32_16x16x32_f16(ain, bim, accre[t], 0, 0, 0);
            accim[t] = __builtin_amdgcn_mfma_f32_16x16x32_f16(are, bim, accim[t], 0, 0, 0);
            accim[t] = __builtin_amdgcn_mfma_f32_16x16x32_f16(aim, bre, accim[t], 0, 0, 0);
        }
    }

    // ================= Walsh epilogue =================
    float z[4][8];
#pragma unroll
    for (int r = 0; r < 4; ++r)
#pragma unroll
        for (int q = 0; q < 8; ++q) z[r][q] = 0.f;

#pragma unroll
    for (int t = 0; t < 4; ++t) {
        int idx = colbase + t * 16;
#pragma unroll
        for (int r = 0; r < 4; ++r) {
            float cr = accre[t][r], ci = accim[t][r];
            float p = fmaf(cr, cr, ci * ci);
#pragma unroll
            for (int q = 0; q < 8; ++q)
                z[r][q] += ((idx >> (7 - q)) & 1) ? -p : p;
        }
    }

#pragma unroll
    for (int r = 0; r < 4; ++r)
#pragma unroll
        for (int q = 0; q < 8; ++q) {
            z[r][q] += lshfl<0>(z[r][q], false);
            z[r][q] += lshfl<1>(z[r][q], false);
            z[r][q] += lshfl<2>(z[r][q], false);
            z[r][q] += lshfl<3>(z[r][q], false);
        }

    if ((lane & 15) < 8) {
        int q = lane & 7;
#pragma unroll
        for (int r = 0; r < 4; ++r)
            zb[cg][rg * 16 + (lane >> 4) * 4 + r][q] = z[r][q];
    }
    __syncthreads();

    if (tid < 256) {
        int row = tid >> 3, q = tid & 7;
        float v = zb[0][row][q] + zb[1][row][q] + zb[2][row][q] + zb[3][row][q];
        out[(b0 + row) * 8 + q] = v;
    }
}

extern "C" void kernel_launch(void* const* d_in, const int* in_sizes, int n_in,
                              void* d_out, int out_size, void* d_ws, size_t ws_size,
                              hipStream_t stream) {
    const float* x      = (const float*)d_in[0];   // (BATCH, 8)
    const float* params = (const float*)d_in[1];   // (2, 8, 3) = 48
    float* out = (float*)d_out;

    f16* Bre  = (f16*)d_ws;                        // 128 KB
    f16* Bim  = Bre + 65536;                       // 128 KB
    u32* flag = (u32*)((char*)d_ws + 262144);      // 4 B

    int batch = in_sizes[0] / 8;

    hipMemsetAsync(flag, 0, 4, stream);

    int blocks = (batch + 31) / 32;
    if (blocks < 32) blocks = 32;                  // producers must exist
    qa_fused<<<blocks, 512, 0, stream>>>(x, params, Bre, Bim, flag, out, batch);
}

// Round 14
// 27.203 us; speedup vs baseline: 3.8949x; 3.8949x over previous
//
#include <hip/hip_runtime.h>

#define DEV __device__ __forceinline__

typedef unsigned u32;
typedef u32 u32x2 __attribute__((ext_vector_type(2)));
typedef _Float16 f16;
typedef f16   f16x8 __attribute__((ext_vector_type(8)));
typedef float f32x4 __attribute__((ext_vector_type(4)));

// ---------- DPP helpers ----------
template<int CTRL>
DEV int dpp_full(int src) {
    return __builtin_amdgcn_update_dpp(src, src, CTRL, 0xF, 0xF, false);
}
template<int CTRL, int RM, int BM>
DEV int dpp_masked(int old, int src) {
    return __builtin_amdgcn_update_dpp(old, src, CTRL, RM, BM, false);
}

// ---------- cross-lane xor-shuffle (r7-proven mix) ----------
template<int B>
DEV float lshfl(float x, bool px) {
    int xi = __float_as_int(x);
    if constexpr (B == 0) {
        return __int_as_float(dpp_full<0xB1>(xi));          // xor1
    } else if constexpr (B == 1) {
        return __int_as_float(dpp_full<0x4E>(xi));          // xor2
    } else if constexpr (B == 2) {
        return __int_as_float(__builtin_amdgcn_ds_swizzle(xi, 0x101F)); // xor4
    } else if constexpr (B == 3) {
        return __int_as_float(dpp_full<0x128>(xi));         // xor8
    } else if constexpr (B == 4) {
        return __int_as_float(__builtin_amdgcn_ds_swizzle(xi, 0x401F)); // xor16
    } else {
        u32x2 r = __builtin_amdgcn_permlane32_swap((u32)xi, (u32)xi, false, false);
        return __int_as_float((int)(px ? r.x : r.y));
    }
}

DEV bool probe32(int lane) {
    u32 p = (u32)((lane >> 5) & 1);
    u32x2 r = __builtin_amdgcn_permlane32_swap(p, p, false, false);
    return r.x == (p ^ 1u);
}

// ---------- complex pair primitives (fp32) ----------
DEV void rx_pair(float& r0, float& i0, float& r1, float& i1, float c, float s) {
    float nr0 = fmaf(c, r0,  s * i1);
    float ni0 = fmaf(c, i0, -s * r1);
    float nr1 = fmaf(c, r1,  s * i0);
    float ni1 = fmaf(c, i1, -s * r0);
    r0 = nr0; i0 = ni0; r1 = nr1; i1 = ni1;
}
DEV void ry_pair(float& r0, float& i0, float& r1, float& i1, float c, float s) {
    float nr0 = fmaf(c, r0, -s * r1);
    float ni0 = fmaf(c, i0, -s * i1);
    float nr1 = fmaf(c, r1,  s * r0);
    float ni1 = fmaf(c, i1,  s * i0);
    r0 = nr0; i0 = ni0; r1 = nr1; i1 = ni1;
}
DEV void rz_amp(float& r, float& i, float c, float ss) {
    float nr = fmaf(c, r, -ss * i);
    float ni = fmaf(c, i,  ss * r);
    r = nr; i = ni;
}

// ---------- gates on flat-index bit B (B = 7 - qubit), r7-verified ----------
template<int B>
DEV void apply_rx(float (&re)[4], float (&im)[4], int lane, bool px, float c, float s) {
    if constexpr (B == 7) {
        rx_pair(re[0], im[0], re[2], im[2], c, s);
        rx_pair(re[1], im[1], re[3], im[3], c, s);
    } else if constexpr (B == 6) {
        rx_pair(re[0], im[0], re[1], im[1], c, s);
        rx_pair(re[2], im[2], re[3], im[3], c, s);
    } else {
#pragma unroll
        for (int k = 0; k < 4; ++k) {
            float pr = lshfl<B>(re[k], px);
            float pi = lshfl<B>(im[k], px);
            re[k] = fmaf(c, re[k],  s * pi);
            im[k] = fmaf(c, im[k], -s * pr);
        }
    }
}
template<int B>
DEV void apply_ry(float (&re)[4], float (&im)[4], int lane, bool px, float c, float s) {
    if constexpr (B == 7) {
        ry_pair(re[0], im[0], re[2], im[2], c, s);
        ry_pair(re[1], im[1], re[3], im[3], c, s);
    } else if constexpr (B == 6) {
        ry_pair(re[0], im[0], re[1], im[1], c, s);
        ry_pair(re[2], im[2], re[3], im[3], c, s);
    } else {
        float ssel = ((lane >> B) & 1) ? s : -s;
#pragma unroll
        for (int k = 0; k < 4; ++k) {
            float pr = lshfl<B>(re[k], px);
            float pi = lshfl<B>(im[k], px);
            re[k] = fmaf(c, re[k], ssel * pr);
            im[k] = fmaf(c, im[k], ssel * pi);
        }
    }
}
template<int B>
DEV void apply_rz(float (&re)[4], float (&im)[4], int lane, float c, float s) {
    if constexpr (B == 7) {
        rz_amp(re[0], im[0], c, -s); rz_amp(re[1], im[1], c, -s);
        rz_amp(re[2], im[2], c,  s); rz_amp(re[3], im[3], c,  s);
    } else if constexpr (B == 6) {
        rz_amp(re[0], im[0], c, -s); rz_amp(re[1], im[1], c,  s);
        rz_amp(re[2], im[2], c, -s); rz_amp(re[3], im[3], c,  s);
    } else {
        float ss = ((lane >> B) & 1) ? s : -s;
#pragma unroll
        for (int k = 0; k < 4; ++k) rz_amp(re[k], im[k], c, ss);
    }
}
template<int BC, int BT>
DEV void apply_cnot(float (&re)[4], float (&im)[4], int lane, bool px) {
    if constexpr (BC == 7 && BT == 6) {
        float tr = re[2], ti = im[2];
        re[2] = re[3]; im[2] = im[3];
        re[3] = tr;    im[3] = ti;
    } else if constexpr (BC == 6) {
        re[1] = lshfl<5>(re[1], px); im[1] = lshfl<5>(im[1], px);
        re[3] = lshfl<5>(re[3], px); im[3] = lshfl<5>(im[3], px);
    } else if constexpr (BC == 5 && BT == 4) {
        bool ctrl = (lane >> 5) & 1;
#pragma unroll
        for (int k = 0; k < 4; ++k) {
            float pr = lshfl<4>(re[k], px);
            float pi = lshfl<4>(im[k], px);
            re[k] = ctrl ? pr : re[k];
            im[k] = ctrl ? pi : im[k];
        }
    } else if constexpr (BC == 4 && BT == 3) {
#pragma unroll
        for (int k = 0; k < 4; ++k) {
            int r = __float_as_int(re[k]), i = __float_as_int(im[k]);
            re[k] = __int_as_float(dpp_masked<0x128, 0xA, 0xF>(r, r));
            im[k] = __int_as_float(dpp_masked<0x128, 0xA, 0xF>(i, i));
        }
    } else if constexpr (BC == 3 && BT == 2) {
#pragma unroll
        for (int k = 0; k < 4; ++k) {
            int r = __float_as_int(re[k]), i = __float_as_int(im[k]);
            int tr = dpp_full<0x1B>(r), ti = dpp_full<0x1B>(i);
            re[k] = __int_as_float(dpp_masked<0x141, 0xF, 0xC>(r, tr));
            im[k] = __int_as_float(dpp_masked<0x141, 0xF, 0xC>(i, ti));
        }
    } else if constexpr (BC == 2 && BT == 1) {
#pragma unroll
        for (int k = 0; k < 4; ++k) {
            int r = __float_as_int(re[k]), i = __float_as_int(im[k]);
            re[k] = __int_as_float(dpp_masked<0x4E, 0xF, 0xA>(r, r));
            im[k] = __int_as_float(dpp_masked<0x4E, 0xF, 0xA>(i, i));
        }
    } else {
#pragma unroll
        for (int k = 0; k < 4; ++k) {
            re[k] = __int_as_float(dpp_full<0xB4>(__float_as_int(re[k])));
            im[k] = __int_as_float(dpp_full<0xB4>(__float_as_int(im[k])));
        }
    }
}

// ---------- kernel 1: build U as packed MFMA B-operand, COALESCED stores ----------
// 32 blocks x 512 thr (8 waves). Wave w simulates basis state j = gid*8+w.
// LDS transpose -> each thread emits ONE 16B store (f16x8 = 8 consecutive j),
// matching the fragment granule: half_index = (kb*256+idx)*32 + joff + 0..7.

__global__ __launch_bounds__(512) void qa_genU(
    const float* __restrict__ params, f16* __restrict__ Bre, f16* __restrict__ Bim)
{
    __shared__ float gs[96];
    __shared__ f16 Lr[8][256];
    __shared__ f16 Li[8][256];

    int tid  = threadIdx.x;
    int w    = tid >> 6, lane = tid & 63;
    int j    = blockIdx.x * 8 + w;
    bool px  = probe32(lane);

    if (tid < 48) {
        float th = params[tid] * 0.5f;
        gs[2 * tid]     = __cosf(th);
        gs[2 * tid + 1] = __sinf(th);
    }
    __syncthreads();

    // basis state e_j
    float re[4], im[4];
#pragma unroll
    for (int k = 0; k < 4; ++k) {
        re[k] = ((j >> 6) == k && (j & 63) == lane) ? 1.f : 0.f;
        im[k] = 0.f;
    }

#define VQ(l, i) { const int jj = (l) * 24 + (i) * 3;                       \
                   apply_ry<7 - (i)>(re, im, lane, px, gs[2*jj],   gs[2*jj+1]); \
                   apply_rz<7 - (i)>(re, im, lane,     gs[2*jj+2], gs[2*jj+3]); }
#define CN(i)    apply_cnot<7 - (i), 6 - (i)>(re, im, lane, px);
#define RXQ(l,i) { const int jj = (l) * 24 + (i) * 3 + 2;                   \
                   apply_rx<7 - (i)>(re, im, lane, px, gs[2*jj], gs[2*jj+1]); }
#define LAYER(l) \
    VQ(l,0) CN(0) VQ(l,1) CN(1) VQ(l,2) CN(2) VQ(l,3) CN(3) \
    VQ(l,4) CN(4) VQ(l,5) CN(5) VQ(l,6) CN(6) VQ(l,7)       \
    RXQ(l,0) RXQ(l,1) RXQ(l,2) RXQ(l,3) RXQ(l,4) RXQ(l,5) RXQ(l,6) RXQ(l,7)

    LAYER(0)
    LAYER(1)
#undef LAYER
#undef RXQ
#undef CN
#undef VQ

#pragma unroll
    for (int k = 0; k < 4; ++k) {
        int idx = k * 64 + lane;
        Lr[w][idx] = (f16)re[k];
        Li[w][idx] = (f16)im[k];
    }
    __syncthreads();

    // writeout: thread t<256 -> Bre[idx=t], t>=256 -> Bim[idx=t-256]
    {
        int idx  = tid & 255;
        bool isim = tid >= 256;
        const f16* src = isim ? &Li[0][0] : &Lr[0][0];
        f16x8 v;
#pragma unroll
        for (int wv = 0; wv < 8; ++wv) v[wv] = src[wv * 256 + idx];
        f16* dst = isim ? Bim : Bre;
        int kb = blockIdx.x >> 2, joff = (blockIdx.x & 3) * 8;
        *reinterpret_cast<f16x8*>(&dst[(kb * 256 + idx) * 32 + joff]) = v;
    }
}

// ---------- kernel 2: encode + GEMM + Walsh readout (r10-verified, unchanged) ----------

__global__ __launch_bounds__(512, 2) void qa_gemm(
    const float* __restrict__ x,
    const f16* __restrict__ Bre, const f16* __restrict__ Bim,
    float* __restrict__ out, int batch)
{
    __shared__ __align__(16) f16 Ar[32 * 256];
    __shared__ __align__(16) f16 Ai[32 * 256];
    __shared__ float zb[4][32][8];

    int tid  = threadIdx.x;
    int w    = tid >> 6, lane = tid & 63;
    int rg   = w >> 2,   cg   = w & 3;
    int b0   = blockIdx.x * 32;
    if (b0 >= batch) return;

    // ---- encode rows w*4 .. w*4+3 into swizzled A LDS (fp16) ----
    int pcl = __popc((u32)lane);
    const int kpc[4] = { 0, 1, 1, 2 };
#pragma unroll
    for (int e = 0; e < 4; ++e) {
        int rl = w * 4 + e;
        const float* xb = x + (b0 + rl) * 8;
        float4 xlo = *(const float4*)xb;
        float4 xhi = *(const float4*)(xb + 4);
        float c_[8], s_[8];
        __sincosf(xlo.x * 0.5f, &s_[0], &c_[0]);
        __sincosf(xlo.y * 0.5f, &s_[1], &c_[1]);
        __sincosf(xlo.z * 0.5f, &s_[2], &c_[2]);
        __sincosf(xlo.w * 0.5f, &s_[3], &c_[3]);
        __sincosf(xhi.x * 0.5f, &s_[4], &c_[4]);
        __sincosf(xhi.y * 0.5f, &s_[5], &c_[5]);
        __sincosf(xhi.z * 0.5f, &s_[6], &c_[6]);
        __sincosf(xhi.w * 0.5f, &s_[7], &c_[7]);

        float m6;
        m6  = ((lane >> 5) & 1) ? s_[2] : c_[2];
        m6 *= ((lane >> 4) & 1) ? s_[3] : c_[3];
        m6 *= ((lane >> 3) & 1) ? s_[4] : c_[4];
        m6 *= ((lane >> 2) & 1) ? s_[5] : c_[5];
        m6 *= ((lane >> 1) & 1) ? s_[6] : c_[6];
        m6 *= ( lane       & 1) ? s_[7] : c_[7];
        float kf[4] = { c_[0] * c_[1], c_[0] * s_[1], s_[0] * c_[1], s_[0] * s_[1] };
        int sw = (rl & 7) << 3;
#pragma unroll
        for (int k = 0; k < 4; ++k) {
            float mk = m6 * kf[k];
            int p = pcl + kpc[k];
            float sgn = (p & 2) ? -mk : mk;
            float vre = (p & 1) ? 0.f : sgn;
            float vim = (p & 1) ? -sgn : 0.f;
            int j  = k * 64 + lane;
            int hi = rl * 256 + (j ^ sw);
            Ar[hi] = (f16)vre;
            Ai[hi] = (f16)vim;
        }
    }
    __syncthreads();

    // ---- K loop: 8 steps of 32, 16 MFMAs each ----
    f32x4 accre[4], accim[4];
#pragma unroll
    for (int t = 0; t < 4; ++t) { accre[t] = (f32x4)0.f; accim[t] = (f32x4)0.f; }

    int colbase = cg * 64 + (lane & 15);
    int arow    = rg * 16 + (lane & 15);
    int kg      = lane >> 4;
    const f16x8* B8re = reinterpret_cast<const f16x8*>(Bre);
    const f16x8* B8im = reinterpret_cast<const f16x8*>(Bim);

#pragma unroll
    for (int kb = 0; kb < 8; ++kb) {
        int afi = arow * 32 + ((kb * 4 + kg) ^ (arow & 7));
        f16x8 are = *reinterpret_cast<const f16x8*>(&Ar[afi * 8]);
        f16x8 aim = *reinterpret_cast<const f16x8*>(&Ai[afi * 8]);
        f16x8 ain;
#pragma unroll
        for (int i = 0; i < 8; ++i) ain[i] = -aim[i];
#pragma unroll
        for (int t = 0; t < 4; ++t) {
            int idx = colbase + t * 16;
            int bo  = (kb * 256 + idx) * 4 + kg;
            f16x8 bre = B8re[bo];
            f16x8 bim = B8im[bo];
            accre[t] = __builtin_amdgcn_mfma_f32_16x16x32_f16(are, bre, accre[t], 0, 0, 0);
            accre[t] = __builtin_amdgcn_mfma_f32_16x16x32_f16(ain, bim, accre[t], 0, 0, 0);
            accim[t] = __builtin_amdgcn_mfma_f32_16x16x32_f16(are, bim, accim[t], 0, 0, 0);
            accim[t] = __builtin_amdgcn_mfma_f32_16x16x32_f16(aim, bre, accim[t], 0, 0, 0);
        }
    }

    // ---- Walsh epilogue ----
    float z[4][8];
#pragma unroll
    for (int r = 0; r < 4; ++r)
#pragma unroll
        for (int q = 0; q < 8; ++q) z[r][q] = 0.f;

#pragma unroll
    for (int t = 0; t < 4; ++t) {
        int idx = colbase + t * 16;
#pragma unroll
        for (int r = 0; r < 4; ++r) {
            float cr = accre[t][r], ci = accim[t][r];
            float p = fmaf(cr, cr, ci * ci);
#pragma unroll
            for (int q = 0; q < 8; ++q)
                z[r][q] += ((idx >> (7 - q)) & 1) ? -p : p;
        }
    }

#pragma unroll
    for (int r = 0; r < 4; ++r)
#pragma unroll
        for (int q = 0; q < 8; ++q) {
            z[r][q] += lshfl<0>(z[r][q], false);
            z[r][q] += lshfl<1>(z[r][q], false);
            z[r][q] += lshfl<2>(z[r][q], false);
            z[r][q] += lshfl<3>(z[r][q], false);
        }

    if ((lane & 15) < 8) {
        int q = lane & 7;
#pragma unroll
        for (int r = 0; r < 4; ++r)
            zb[cg][rg * 16 + (lane >> 4) * 4 + r][q] = z[r][q];
    }
    __syncthreads();

    if (tid < 256) {
        int row = tid >> 3, q = tid & 7;
        float v = zb[0][row][q] + zb[1][row][q] + zb[2][row][q] + zb[3][row][q];
        out[(b0 + row) * 8 + q] = v;
    }
}

extern "C" void kernel_launch(void* const* d_in, const int* in_sizes, int n_in,
                              void* d_out, int out_size, void* d_ws, size_t ws_size,
                              hipStream_t stream) {
    const float* x      = (const float*)d_in[0];   // (BATCH, 8)
    const float* params = (const float*)d_in[1];   // (2, 8, 3) = 48
    float* out = (float*)d_out;

    f16* Bre = (f16*)d_ws;              // 128 KB
    f16* Bim = Bre + 65536;             // 128 KB

    int batch = in_sizes[0] / 8;

    qa_genU<<<32, 512, 0, stream>>>(params, Bre, Bim);

    int blocks = (batch + 31) / 32;
    qa_gemm<<<blocks, 512, 0, stream>>>(x, Bre, Bim, out, batch);
}